// Round 1
// baseline (1147.737 us; speedup 1.0000x reference)
//
#include <hip/hip_runtime.h>
#include <stdint.h>

// Triangle multiplication (outgoing), N=768, C=128.
// Pipeline:
//   K0: build interleaved bf16 weight matrix Wcat[768][128]:
//       rows 4c..4c+3 = wp[2c], wg[2c], wp[2c+1], wg[2c+1]  (c=0..127)
//       rows 512..639 = w_glin ; rows 640..767 = w_out
//   K1: per 64-point tile: LN(pair) -> bf16 frags; MFMA D = Wcat_chunk @ Xn^T.
//       Lane holds (proj_a,gate_a,proj_b,gate_b) per channel in its 4 acc regs.
//       Writes a_t[c][i][k], b_t[c][j][k] (bf16, channel-major) and
//       g[point][c] = sigmoid(xn @ w_glin^T) (bf16).
//   K2: 128 batched 768x768x768 bf16 GEMMs (m97 structure) -> o_t[c][i][j] bf16.
//   K3: transpose-stage o_t, LN over c, MFMA with w_out, multiply by g,
//       write out[i][j][c] fp32.
// Workspace: 4*150994944 + 196608 = 604176384 bytes.

#define NN_F (768 * 768)

typedef float f32x4 __attribute__((ext_vector_type(4)));
typedef __bf16 bf16x8 __attribute__((ext_vector_type(8)));

#define AS1 __attribute__((address_space(1)))
#define AS3 __attribute__((address_space(3)))

__device__ __forceinline__ unsigned short f2b(float f) {
  unsigned u = __builtin_bit_cast(unsigned, f);
  u = u + 0x7fffu + ((u >> 16) & 1u);
  return (unsigned short)(u >> 16);
}
__device__ __forceinline__ float b2f(unsigned short s) {
  return __builtin_bit_cast(float, ((unsigned)s) << 16);
}
__device__ __forceinline__ float sigf(float x) {
  return 1.0f / (1.0f + __expf(-x));
}

// ---------------------------------------------------------------- K0
__global__ __launch_bounds__(256) void k0_weights(
    const float* __restrict__ w_proj, const float* __restrict__ w_gate,
    const float* __restrict__ w_glin, const float* __restrict__ w_out,
    unsigned short* __restrict__ Wcat) {
  int idx = blockIdx.x * 256 + threadIdx.x;  // 768*128 total
  int r = idx >> 7, k = idx & 127;
  float v;
  if (r < 512) {
    int c = r >> 2, tt = r & 3;
    int row = 2 * c + (tt >> 1);
    v = (tt & 1) ? w_gate[row * 128 + k] : w_proj[row * 128 + k];
  } else if (r < 640) {
    v = w_glin[(r - 512) * 128 + k];
  } else {
    v = w_out[(r - 640) * 128 + k];
  }
  Wcat[idx] = f2b(v);
}

// ---------------------------------------------------------------- K1
__global__ __launch_bounds__(256) void k1_proj(
    const float* __restrict__ pair, const float* __restrict__ lnw,
    const float* __restrict__ lnb, const unsigned short* __restrict__ Wcat,
    unsigned short* __restrict__ a_t, unsigned short* __restrict__ b_t,
    unsigned short* __restrict__ g) {
  __shared__ float xs[64 * 132];          // raw pair tile, padded rows
  __shared__ float red[8][64];
  __shared__ float muA[64], rsA[64];
  __shared__ unsigned short wbuf[32 * 512];  // frag-linear weight chunk, 32KB

  const int t = threadIdx.x;
  const int l = t & 63, w = t >> 6;
  const int lm = l & 15, lq = l >> 4;
  const size_t p0 = (size_t)blockIdx.x * 64;

  // Phase A: coalesced load of 64 points x 128 channels
  const float* src = pair + p0 * 128;
#pragma unroll
  for (int v = 0; v < 8; ++v) {
    int fi = (v * 256 + t) * 4;
    int p = fi >> 7, c = fi & 127;
    f32x4 d = *(const f32x4*)(src + fi);
    *(f32x4*)&xs[p * 132 + c] = d;
  }
  __syncthreads();
  // Phase B: LN stats
  {
    int p = t & 63, q = t >> 6;
    float s1 = 0.f, s2 = 0.f;
#pragma unroll
    for (int cc = 0; cc < 32; ++cc) {
      float x = xs[p * 132 + q * 32 + cc];
      s1 += x;
      s2 += x * x;
    }
    red[q][p] = s1;
    red[q + 4][p] = s2;
  }
  __syncthreads();
  if (t < 64) {
    float s1 = red[0][t] + red[1][t] + red[2][t] + red[3][t];
    float s2 = red[4][t] + red[5][t] + red[6][t] + red[7][t];
    float mu = s1 * (1.f / 128.f);
    float var = s2 * (1.f / 128.f) - mu * mu;
    muA[t] = mu;
    rsA[t] = rsqrtf(var + 1e-5f);
  }
  __syncthreads();
  // Phase C: build B-operand frags (normalized, bf16). B[n=lane&15][k=lq*8+j]
  bf16x8 xfr[4][4];
#pragma unroll
  for (int pt = 0; pt < 4; ++pt) {
    int p = pt * 16 + lm;
    float mu = muA[p], rs = rsA[p];
#pragma unroll
    for (int kt = 0; kt < 4; ++kt) {
      int ks = kt * 32 + lq * 8;
      union { bf16x8 v; unsigned short u[8]; } fr;
#pragma unroll
      for (int j = 0; j < 8; ++j) {
        float x = xs[p * 132 + ks + j];
        fr.u[j] = f2b((x - mu) * rs * lnw[ks + j] + lnb[ks + j]);
      }
      xfr[pt][kt] = fr.v;
    }
  }
  // Phase D: 5 chunks of 128 weight rows (4x pg, 1x glin)
  for (int wc = 0; wc < 5; ++wc) {
    __syncthreads();
    int r0 = wc * 128;
#pragma unroll
    for (int at2 = 0; at2 < 2; ++at2) {
      int at = w * 2 + at2;
#pragma unroll
      for (int kt = 0; kt < 4; ++kt) {
        const unsigned short* gp =
            Wcat + (size_t)(r0 + at * 16 + lm) * 128 + kt * 32 + lq * 8;
        __builtin_amdgcn_global_load_lds((const AS1 void*)gp,
                                         (AS3 void*)(wbuf + (at * 4 + kt) * 512),
                                         16, 0, 0);
      }
    }
    __builtin_amdgcn_s_waitcnt(0x0f70);  // vmcnt(0)
    f32x4 acc[2][4];
#pragma unroll
    for (int a2 = 0; a2 < 2; ++a2)
#pragma unroll
      for (int pt = 0; pt < 4; ++pt) acc[a2][pt] = (f32x4){0.f, 0.f, 0.f, 0.f};
#pragma unroll
    for (int at2 = 0; at2 < 2; ++at2) {
      int at = w * 2 + at2;
      bf16x8 af[4];
#pragma unroll
      for (int kt = 0; kt < 4; ++kt)
        af[kt] = *(const bf16x8*)&wbuf[(at * 4 + kt) * 512 + l * 8];
#pragma unroll
      for (int pt = 0; pt < 4; ++pt)
#pragma unroll
        for (int kt = 0; kt < 4; ++kt)
          acc[at2][pt] = __builtin_amdgcn_mfma_f32_16x16x32_bf16(
              af[kt], xfr[pt][kt], acc[at2][pt], 0, 0, 0);
    }
    // Epilogue: lane = point (col), regs = 4 consecutive weight rows
#pragma unroll
    for (int at2 = 0; at2 < 2; ++at2) {
      int rbase = r0 + (w * 2 + at2) * 16 + lq * 4;
#pragma unroll
      for (int pt = 0; pt < 4; ++pt) {
        f32x4 d = acc[at2][pt];
        size_t point = p0 + pt * 16 + lm;
        if (wc < 4) {
          int c = rbase >> 2;
          a_t[(size_t)c * NN_F + point] = f2b(d[0] * sigf(d[1]));
          b_t[(size_t)c * NN_F + point] = f2b(d[2] * sigf(d[3]));
        } else {
          int co = rbase - 512;
          union { unsigned long long ll; unsigned short u[4]; } pk;
          pk.u[0] = f2b(sigf(d[0]));
          pk.u[1] = f2b(sigf(d[1]));
          pk.u[2] = f2b(sigf(d[2]));
          pk.u[3] = f2b(sigf(d[3]));
          *(unsigned long long*)&g[point * 128 + co] = pk.ll;
        }
      }
    }
  }
}

// ---------------------------------------------------------------- K2
__global__ __launch_bounds__(256) void k2_einsum(
    const unsigned short* __restrict__ a_t, const unsigned short* __restrict__ b_t,
    unsigned short* __restrict__ o_t) {
  __shared__ unsigned short As[128 * 32];
  __shared__ unsigned short Bs[128 * 32];
  const int t = threadIdx.x;
  const int l = t & 63, w = t >> 6;
  const int lm = l & 15, lq = l >> 4;
  const int c = blockIdx.z;
  const int m0 = blockIdx.y * 128, n0 = blockIdx.x * 128;
  const unsigned short* Ac = a_t + (size_t)c * NN_F;
  const unsigned short* Bc = b_t + (size_t)c * NN_F;
  const int wi = w >> 1, wj = w & 1;
  const int lrow = l >> 2, lk = (l & 3) * 8;
  f32x4 acc[4][4];
#pragma unroll
  for (int ti = 0; ti < 4; ++ti)
#pragma unroll
    for (int tj = 0; tj < 4; ++tj) acc[ti][tj] = (f32x4){0.f, 0.f, 0.f, 0.f};

  for (int kb = 0; kb < 24; ++kb) {
    __syncthreads();
#pragma unroll
    for (int h = 0; h < 2; ++h) {
      int row = w * 32 + h * 16 + lrow;
      __builtin_amdgcn_global_load_lds(
          (const AS1 void*)(Ac + (size_t)(m0 + row) * 768 + kb * 32 + lk),
          (AS3 void*)(As + (w * 32 + h * 16) * 32), 16, 0, 0);
      __builtin_amdgcn_global_load_lds(
          (const AS1 void*)(Bc + (size_t)(n0 + row) * 768 + kb * 32 + lk),
          (AS3 void*)(Bs + (w * 32 + h * 16) * 32), 16, 0, 0);
    }
    __builtin_amdgcn_s_waitcnt(0x0f70);  // vmcnt(0)
    __syncthreads();
    bf16x8 af[4], bfr[4];
#pragma unroll
    for (int ti = 0; ti < 4; ++ti)
      af[ti] = *(const bf16x8*)&As[(wi * 64 + ti * 16 + lm) * 32 + lq * 8];
#pragma unroll
    for (int tj = 0; tj < 4; ++tj)
      bfr[tj] = *(const bf16x8*)&Bs[(wj * 64 + tj * 16 + lm) * 32 + lq * 8];
#pragma unroll
    for (int ti = 0; ti < 4; ++ti)
#pragma unroll
      for (int tj = 0; tj < 4; ++tj)
        acc[ti][tj] = __builtin_amdgcn_mfma_f32_16x16x32_bf16(
            af[ti], bfr[tj], acc[ti][tj], 0, 0, 0);
  }
  unsigned short* Oc = o_t + (size_t)c * NN_F;
#pragma unroll
  for (int ti = 0; ti < 4; ++ti) {
    int ib = m0 + wi * 64 + ti * 16 + lq * 4;
#pragma unroll
    for (int tj = 0; tj < 4; ++tj) {
      int j = n0 + wj * 64 + tj * 16 + lm;
      f32x4 d = acc[ti][tj];
#pragma unroll
      for (int r = 0; r < 4; ++r) Oc[(size_t)(ib + r) * 768 + j] = f2b(d[r]);
    }
  }
}

// ---------------------------------------------------------------- K3
__global__ __launch_bounds__(256) void k3_out(
    const unsigned short* __restrict__ o_t, const float* __restrict__ lnw,
    const float* __restrict__ lnb, const unsigned short* __restrict__ Wcat,
    const unsigned short* __restrict__ g, float* __restrict__ out) {
  __shared__ float ys[64 * 132];
  __shared__ float red[8][64];
  __shared__ float muA[64], rsA[64];
  __shared__ unsigned short wbuf[32 * 512];

  const int t = threadIdx.x;
  const int l = t & 63, w = t >> 6;
  const int lm = l & 15, lq = l >> 4;
  const size_t pblk = (size_t)blockIdx.x * 64;
  const int i = (int)(pblk / 768), j0 = (int)(pblk % 768);

  // Early async stage of w_out frags (rows 640..767 of Wcat)
#pragma unroll
  for (int at2 = 0; at2 < 2; ++at2) {
    int at = w * 2 + at2;
#pragma unroll
    for (int kt = 0; kt < 4; ++kt) {
      const unsigned short* gp =
          Wcat + (size_t)(640 + at * 16 + lm) * 128 + kt * 32 + lq * 8;
      __builtin_amdgcn_global_load_lds(
          (const AS1 void*)gp, (AS3 void*)(wbuf + (at * 4 + kt) * 512), 16, 0, 0);
    }
  }

  // Phase A: transposed stage of o_t[c][i][j0..j0+63] -> ys[j][c]
  {
    int jj = t & 63, cg = t >> 6;
#pragma unroll
    for (int it = 0; it < 32; ++it) {
      int cc = cg * 32 + it;
      ys[jj * 132 + cc] = b2f(o_t[(size_t)cc * NN_F + (size_t)i * 768 + j0 + jj]);
    }
  }
  __syncthreads();
  // LN stats over c
  {
    int p = t & 63, q = t >> 6;
    float s1 = 0.f, s2 = 0.f;
#pragma unroll
    for (int cc = 0; cc < 32; ++cc) {
      float x = ys[p * 132 + q * 32 + cc];
      s1 += x;
      s2 += x * x;
    }
    red[q][p] = s1;
    red[q + 4][p] = s2;
  }
  __syncthreads();
  if (t < 64) {
    float s1 = red[0][t] + red[1][t] + red[2][t] + red[3][t];
    float s2 = red[4][t] + red[5][t] + red[6][t] + red[7][t];
    float mu = s1 * (1.f / 128.f);
    float var = s2 * (1.f / 128.f) - mu * mu;
    muA[t] = mu;
    rsA[t] = rsqrtf(var + 1e-5f);
  }
  __syncthreads();
  // frags of LN'd einsum output
  bf16x8 yfr[4][4];
#pragma unroll
  for (int pt = 0; pt < 4; ++pt) {
    int p = pt * 16 + lm;
    float mu = muA[p], rs = rsA[p];
#pragma unroll
    for (int kt = 0; kt < 4; ++kt) {
      int ks = kt * 32 + lq * 8;
      union { bf16x8 v; unsigned short u[8]; } fr;
#pragma unroll
      for (int j = 0; j < 8; ++j) {
        float x = ys[p * 132 + ks + j];
        fr.u[j] = f2b((x - mu) * rs * lnw[ks + j] + lnb[ks + j]);
      }
      yfr[pt][kt] = fr.v;
    }
  }
  __builtin_amdgcn_s_waitcnt(0x0f70);  // vmcnt(0): wbuf staged
  f32x4 acc[2][4];
#pragma unroll
  for (int a2 = 0; a2 < 2; ++a2)
#pragma unroll
    for (int pt = 0; pt < 4; ++pt) acc[a2][pt] = (f32x4){0.f, 0.f, 0.f, 0.f};
#pragma unroll
  for (int at2 = 0; at2 < 2; ++at2) {
    int at = w * 2 + at2;
    bf16x8 af[4];
#pragma unroll
    for (int kt = 0; kt < 4; ++kt)
      af[kt] = *(const bf16x8*)&wbuf[(at * 4 + kt) * 512 + l * 8];
#pragma unroll
    for (int pt = 0; pt < 4; ++pt)
#pragma unroll
      for (int kt = 0; kt < 4; ++kt)
        acc[at2][pt] = __builtin_amdgcn_mfma_f32_16x16x32_bf16(
            af[kt], yfr[pt][kt], acc[at2][pt], 0, 0, 0);
  }
  // Epilogue: out[point][o..o+3] = D * g (g is already sigmoid'ed)
#pragma unroll
  for (int at2 = 0; at2 < 2; ++at2) {
    int ob = (w * 2 + at2) * 16 + lq * 4;
#pragma unroll
    for (int pt = 0; pt < 4; ++pt) {
      size_t point = pblk + pt * 16 + lm;
      f32x4 d = acc[at2][pt];
      union { unsigned long long ll; unsigned short u[4]; } pk;
      pk.ll = *(const unsigned long long*)(g + point * 128 + ob);
      f32x4 r;
      r[0] = d[0] * b2f(pk.u[0]);
      r[1] = d[1] * b2f(pk.u[1]);
      r[2] = d[2] * b2f(pk.u[2]);
      r[3] = d[3] * b2f(pk.u[3]);
      *(f32x4*)&out[point * 128 + ob] = r;
    }
  }
}

// ---------------------------------------------------------------- launch
extern "C" void kernel_launch(void* const* d_in, const int* in_sizes, int n_in,
                              void* d_out, int out_size, void* d_ws, size_t ws_size,
                              hipStream_t stream) {
  const float* pair = (const float*)d_in[0];
  const float* ln_in_w = (const float*)d_in[1];
  const float* ln_in_b = (const float*)d_in[2];
  const float* w_proj = (const float*)d_in[3];
  const float* w_gate = (const float*)d_in[4];
  const float* ln_c_w = (const float*)d_in[5];
  const float* ln_c_b = (const float*)d_in[6];
  const float* w_out = (const float*)d_in[7];
  const float* w_glin = (const float*)d_in[8];
  float* out = (float*)d_out;

  char* ws = (char*)d_ws;
  const size_t SZ = (size_t)150994944;  // 128*768*768*2 bytes
  unsigned short* a_t = (unsigned short*)(ws);
  unsigned short* b_t = (unsigned short*)(ws + SZ);
  unsigned short* o_t = (unsigned short*)(ws + 2 * SZ);
  unsigned short* g = (unsigned short*)(ws + 3 * SZ);
  unsigned short* Wcat = (unsigned short*)(ws + 4 * SZ);

  hipLaunchKernelGGL(k0_weights, dim3(384), dim3(256), 0, stream,
                     w_proj, w_gate, w_glin, w_out, Wcat);
  hipLaunchKernelGGL(k1_proj, dim3(9216), dim3(256), 0, stream,
                     pair, ln_in_w, ln_in_b, Wcat, a_t, b_t, g);
  hipLaunchKernelGGL(k2_einsum, dim3(6, 6, 128), dim3(256), 0, stream,
                     a_t, b_t, o_t);
  hipLaunchKernelGGL(k3_out, dim3(9216), dim3(256), 0, stream,
                     o_t, ln_c_w, ln_c_b, Wcat, g, out);
}